// Round 16
// baseline (77.475 us; speedup 1.0000x reference)
//
#include <hip/hip_runtime.h>

typedef unsigned long long u64;
typedef float f32x2 __attribute__((ext_vector_type(2)));

#define CSC 2.8853900817779268f   // 2*log2(e): tanh(x) = 1 - 2/(exp2(x*CSC)+1)
#define NBIN 4096
#define CAP  256
#define BT   8
#define MAXJ 16                   // select supports N <= 16*4096

__device__ __forceinline__ f32x2 fma2(f32x2 a, f32x2 b, f32x2 c) {
#if __has_builtin(__builtin_elementwise_fma)
  return __builtin_elementwise_fma(a, b, c);   // -> v_pk_fma_f32
#else
  f32x2 r; r.x = fmaf(a.x, b.x, c.x); r.y = fmaf(a.y, b.y, c.y); return r;
#endif
}

// ---------- sortable key packing ----------
__device__ __forceinline__ unsigned ord32(float f) {
  unsigned u = __float_as_uint(f);
  return (u & 0x80000000u) ? ~u : (u | 0x80000000u);
}
// max-key: descending score, ties -> ascending index (jax.lax.top_k semantics)
__device__ __forceinline__ u64 packMax(float f, int n) {
  return ((u64)ord32(f) << 32) | (unsigned)(~(unsigned)n);
}

// ================= prep: 4x4 register-tiled projection, SWAPPED pk layout (r15) =================
// positions (p0,p1,p2,p3) hold orig d (p0, p0+2, p0+1, p0+3); also writes swapped vS.
__global__ void __launch_bounds__(256)
prep_kernel(const float* __restrict__ basket, const float* __restrict__ item,
            const float* __restrict__ Wb, const float* __restrict__ Wi,
            const float* __restrict__ v,
            float* __restrict__ ipE, float* __restrict__ bpE, float* __restrict__ vS,
            int N, int B, int nItemBlk) {
  __shared__ float itS[64][64];   // [e][row]
  __shared__ float WT[64][64];    // [e][d]
  int tid = threadIdx.x;

  bool isBasket = (blockIdx.x >= nItemBlk);
  const float* src = isBasket ? basket : item;
  const float* W   = isBasket ? Wb : Wi;
  float* dst       = isBasket ? bpE : ipE;
  int r0   = isBasket ? (blockIdx.x - nItemBlk) * 64 : blockIdx.x * 64;
  int rMax = isBasket ? B : N;

  if (blockIdx.x == (unsigned)nItemBlk && tid < 64) {  // swapped v copy
    int q = tid & 3;
    int sidx = tid + (q == 1 ? 1 : 0) - (q == 2 ? 1 : 0);
    vS[tid] = v[sidx];
  }

  {
    int r = tid & 63, ec = (tid >> 6) * 16;
    const float4* sp = (const float4*)(src + (size_t)(r0 + r) * 64 + ec);
    bool ok = (r0 + r) < rMax;
#pragma unroll
    for (int q = 0; q < 4; ++q) {
      float4 t = ok ? sp[q] : make_float4(0.f, 0.f, 0.f, 0.f);
      itS[ec + 4 * q + 0][r] = t.x;
      itS[ec + 4 * q + 1][r] = t.y;
      itS[ec + 4 * q + 2][r] = t.z;
      itS[ec + 4 * q + 3][r] = t.w;
    }
    const float4* wp = (const float4*)(W + (size_t)r * 64 + ec);
#pragma unroll
    for (int q = 0; q < 4; ++q) {
      float4 t = wp[q];
      WT[ec + 4 * q + 0][r] = t.x;
      WT[ec + 4 * q + 1][r] = t.y;
      WT[ec + 4 * q + 2][r] = t.z;
      WT[ec + 4 * q + 3][r] = t.w;
    }
  }
  __syncthreads();

  int ti = tid & 15, td = tid >> 4;
  float acc[4][4];
#pragma unroll
  for (int i = 0; i < 4; ++i)
#pragma unroll
    for (int j = 0; j < 4; ++j) acc[i][j] = 0.f;

#pragma unroll 8
  for (int e = 0; e < 64; ++e) {
    float4 ri = *(const float4*)&itS[e][4 * ti];
    float4 wd = *(const float4*)&WT[e][4 * td];
    float rr[4] = {ri.x, ri.y, ri.z, ri.w};
    float ww[4] = {wd.x, wd.y, wd.z, wd.w};
#pragma unroll
    for (int i = 0; i < 4; ++i)
#pragma unroll
      for (int j = 0; j < 4; ++j) acc[i][j] = fmaf(rr[i], ww[j], acc[i][j]);
  }

#pragma unroll
  for (int i = 0; i < 4; ++i) {
    int gr = r0 + 4 * ti + i;
    if (gr < rMax) {
      float4 o;                   // middle-two swapped: (d0, d2, d1, d3)
      o.x = __builtin_amdgcn_exp2f(acc[i][0] * CSC);
      o.y = __builtin_amdgcn_exp2f(acc[i][2] * CSC);
      o.z = __builtin_amdgcn_exp2f(acc[i][1] * CSC);
      o.w = __builtin_amdgcn_exp2f(acc[i][3] * CSC);
      *(float4*)(dst + (size_t)gr * 64 + 4 * td) = o;
    }
  }
}

// ================= scores: pk 4-term rational, g-OUTER / b-INNER =================
__global__ void __launch_bounds__(256)
scores_kernel(const float* __restrict__ ipE, const float* __restrict__ bpE,
              const float* __restrict__ v, const float* __restrict__ vS,
              float* __restrict__ scores, int N, int B) {
  int tid = threadIdx.x;
  int b0 = blockIdx.y * BT;
  if (b0 > B - BT) b0 = B - BT;              // duplicate-safe clamp
  int n = blockIdx.x * 256 + tid;
  if (n >= N) return;

  float svf;
  {
    double sv = 0.0;
#pragma unroll
    for (int d = 0; d < 64; ++d) sv += (double)v[d]; // uniform, original order
    svf = (float)sv;
  }

  float acc[BT];
#pragma unroll
  for (int b = 0; b < BT; ++b) acc[b] = 0.f;

  f32x2 one2; one2.x = 1.f; one2.y = 1.f;

#pragma unroll
  for (int half = 0; half < 2; ++half) {
    const f32x2* p   = (const f32x2*)(ipE + (size_t)n * 64 + half * 32);
    const f32x2* vv2 = (const f32x2*)(vS + half * 32);   // uniform -> s_load
    const float* ebB = bpE + (size_t)b0 * 64 + half * 32;

#pragma unroll
    for (int g = 0; g < 8; ++g) {        // pair-group outer: eh loaded ONCE per g
      f32x2 ehA = p[2 * g];              // (E_i d0, E_i d2)
      f32x2 ehB = p[2 * g + 1];          // (E_i d1, E_i d3)
      f32x2 vA = vv2[2 * g], vB = vv2[2 * g + 1];

#pragma unroll
      for (int b = 0; b < BT; ++b) {     // 8 independent acc chains -> ILP
        const f32x2* eb2 = (const f32x2*)(ebB + (size_t)b * 64);  // uniform
        f32x2 XA = fma2(eb2[2 * g], ehA, one2);          // (x0, x2)
        f32x2 XB = fma2(eb2[2 * g + 1], ehB, one2);      // (x1, x3)
        f32x2 PP = XA * XB;                              // (x0x1, x2x3)
        f32x2 T  = vA * XB;                              // (v0x1, v2x3)
        f32x2 NUM = fma2(vB, XA, T);                     // (n01, n23)
        float den = PP.x * PP.y;
        float num = NUM.x * PP.y;
        num = fmaf(NUM.y, PP.x, num);
        float r = __builtin_amdgcn_rcpf(den);            // 1 rcp per 4 terms
        acc[b] = fmaf(num, r, acc[b]);
      }
    }
  }

#pragma unroll
  for (int b = 0; b < BT; ++b)
    scores[(size_t)(b0 + b) * N + n] = fmaf(-2.0f, acc[b], svf);
}

// ================= select: sign-split, 2 blocks per row (r13, unchanged) =================
__global__ void __launch_bounds__(1024)
select_kernel(const float* __restrict__ scores, const float* __restrict__ v,
              int* __restrict__ out, int N, int B, int K) {
  __shared__ int lh[NBIN];
  __shared__ int part[64];
  __shared__ u64 cand[CAP];
  __shared__ int cnt, hHi;
  int tid = threadIdx.x;
  int b = blockIdx.x >> 1, side = blockIdx.x & 1;
  const float* row = scores + (size_t)b * N;
  float sgn = side ? -1.f : 1.f;      // side 1: top-k of -s == bottom-k of s

  for (int i = tid; i < NBIN; i += 1024) lh[i] = 0;
  if (tid == 0) cnt = 0;

  // |score| < R = sum|v_d| strictly (|tanh|<1) -> linear bins over [-R, R]
  float R = 0.f;
#pragma unroll
  for (int d = 0; d < 64; ++d) R += fabsf(v[d]);     // uniform
  float invW = (float)NBIN / (2.f * R);
  __syncthreads();

  // pass 1: load (sign-applied) into REGISTERS + histogram
  float4 v4[MAXJ];
#pragma unroll
  for (int j = 0; j < MAXJ; ++j) {
    int f4 = j * 1024 + tid;
    if (j * 4096 < N && f4 * 4 < N) {
      float4 s4 = *(const float4*)(row + (size_t)f4 * 4);
      s4.x *= sgn; s4.y *= sgn; s4.z *= sgn; s4.w *= sgn;
      v4[j] = s4;
      int n0 = f4 * 4;
      float ss[4] = {s4.x, s4.y, s4.z, s4.w};
#pragma unroll
      for (int c = 0; c < 4; ++c) {
        if (n0 + c < N) {
          int bi = (int)((ss[c] + R) * invW);
          bi = bi < 0 ? 0 : (bi > NBIN - 1 ? NBIN - 1 : bi);
          atomicAdd(&lh[bi], 1);
        }
      }
    }
  }
  __syncthreads();

  if (tid < 64) {                  // 64-bin chunk sums
    int s = 0;
    for (int jj = 0; jj < 64; ++jj) s += lh[tid * 64 + jj];
    part[tid] = s;
  }
  __syncthreads();
  if (tid == 0) {                  // threshold bin from the top (of s')
    int cum = 0, c = 63;
    for (; c > 0; --c) { if (cum + part[c] >= K) break; cum += part[c]; }
    int hh = c * 64 + 63;
    for (;; --hh) { cum += lh[hh]; if (cum >= K || hh == 0) break; }
    hHi = hh;
  }
  __syncthreads();
  int hi = hHi;

  // pass 2: compact from registers
#pragma unroll
  for (int j = 0; j < MAXJ; ++j) {
    int f4 = j * 1024 + tid;
    if (j * 4096 < N && f4 * 4 < N) {
      int n0 = f4 * 4;
      float ss[4] = {v4[j].x, v4[j].y, v4[j].z, v4[j].w};
#pragma unroll
      for (int c = 0; c < 4; ++c) {
        if (n0 + c < N) {
          float s = ss[c];
          int bi = (int)((s + R) * invW);
          bi = bi < 0 ? 0 : (bi > NBIN - 1 ? NBIN - 1 : bi);
          if (bi >= hi) { int i = atomicAdd(&cnt, 1); if (i < CAP) cand[i] = packMax(s, n0 + c); }
        }
      }
    }
  }
  __syncthreads();

  // exact rank, O(C^2); keys unique -> ranks unique & complete
  int tP = cnt < CAP ? cnt : CAP;
  int* dst = out + (side ? (size_t)B * K : 0) + (size_t)b * K;
  for (int i = tid; i < tP; i += 1024) {
    u64 key = cand[i]; int r = 0;
    for (int jj = 0; jj < tP; ++jj) r += (cand[jj] > key);
    if (r < K) dst[r] = (int)(~(unsigned)key);
  }
}

extern "C" void kernel_launch(void* const* d_in, const int* in_sizes, int n_in,
                              void* d_out, int out_size, void* d_ws, size_t ws_size,
                              hipStream_t stream) {
  const float* basket = (const float*)d_in[0];
  const float* item   = (const float*)d_in[1];
  const float* Wb     = (const float*)d_in[2];
  const float* Wi     = (const float*)d_in[3];
  const float* v      = (const float*)d_in[4];
  int D = in_sizes[4];           // 64
  int B = in_sizes[0] / D;       // 128
  int N = in_sizes[1] / D;       // 50000
  int K = out_size / (2 * B);    // 50

  float* scores = (float*)d_ws;                         // B*N floats = 25.6 MB
  float* ipE    = scores + (size_t)B * N;               // N*64 floats = 12.8 MB
  float* bpE    = ipE + (size_t)N * 64;                 // B*64 floats = 32 KB
  float* vS     = bpE + (size_t)B * 64;                 // 64 floats (swapped v)

  int nItemBlk = (N + 63) / 64;
  int nBasBlk  = (B + 63) / 64;
  prep_kernel<<<dim3(nItemBlk + nBasBlk), dim3(256), 0, stream>>>(basket, item, Wb, Wi, v, ipE, bpE, vS, N, B, nItemBlk);

  dim3 gs((N + 255) / 256, (B + BT - 1) / BT);
  scores_kernel<<<gs, dim3(256), 0, stream>>>(ipE, bpE, v, vS, scores, N, B);

  select_kernel<<<dim3(2 * B), dim3(1024), 0, stream>>>(scores, v, (int*)d_out, N, B, K);
}

// Round 17
// 76.127 us; speedup vs baseline: 1.0177x; 1.0177x over previous
//
#include <hip/hip_runtime.h>

typedef unsigned long long u64;
typedef float f32x2 __attribute__((ext_vector_type(2)));

#define CSC 2.8853900817779268f   // 2*log2(e): tanh(x) = 1 - 2/(exp2(x*CSC)+1)
#define NBIN 4096
#define CAP  256
#define BT   8
#define MAXJ 16                   // select supports N <= 16*4096

__device__ __forceinline__ f32x2 fma2(f32x2 a, f32x2 b, f32x2 c) {
#if __has_builtin(__builtin_elementwise_fma)
  return __builtin_elementwise_fma(a, b, c);   // -> v_pk_fma_f32
#else
  f32x2 r; r.x = fmaf(a.x, b.x, c.x); r.y = fmaf(a.y, b.y, c.y); return r;
#endif
}

// ---------- sortable key packing ----------
__device__ __forceinline__ unsigned ord32(float f) {
  unsigned u = __float_as_uint(f);
  return (u & 0x80000000u) ? ~u : (u | 0x80000000u);
}
// max-key: descending score, ties -> ascending index (jax.lax.top_k semantics)
__device__ __forceinline__ u64 packMax(float f, int n) {
  return ((u64)ord32(f) << 32) | (unsigned)(~(unsigned)n);
}

// ================= prep: register-tiled projection, GROUP-INTERLEAVED layout =================
// Each aligned 8-block of output positions holds orig d [0,4,1,5,2,6,3,7]+8j:
// pk lane pairs = (group 2j elem k, group 2j+1 elem k). Permutation applied via
// WT staging column index (free); float4 stores stay natural. vS permuted to match.
__global__ void __launch_bounds__(256)
prep_kernel(const float* __restrict__ basket, const float* __restrict__ item,
            const float* __restrict__ Wb, const float* __restrict__ Wi,
            const float* __restrict__ v,
            float* __restrict__ ipE, float* __restrict__ bpE, float* __restrict__ vS,
            int N, int B, int nItemBlk) {
  __shared__ float itS[64][64];   // [e][row]
  __shared__ float WT[64][64];    // [e][pos]  (d permuted into pos)
  int tid = threadIdx.x;

  bool isBasket = (blockIdx.x >= nItemBlk);
  const float* src = isBasket ? basket : item;
  const float* W   = isBasket ? Wb : Wi;
  float* dst       = isBasket ? bpE : ipE;
  int r0   = isBasket ? (blockIdx.x - nItemBlk) * 64 : blockIdx.x * 64;
  int rMax = isBasket ? B : N;

  if (blockIdx.x == (unsigned)nItemBlk && tid < 64) {  // permuted v copy
    int p = tid & 7;
    int d_off = (p & 1) ? (4 + (p >> 1)) : (p >> 1);
    vS[tid] = v[(tid & ~7) | d_off];
  }

  {
    int r = tid & 63, ec = (tid >> 6) * 16;
    const float4* sp = (const float4*)(src + (size_t)(r0 + r) * 64 + ec);
    bool ok = (r0 + r) < rMax;
#pragma unroll
    for (int q = 0; q < 4; ++q) {
      float4 t = ok ? sp[q] : make_float4(0.f, 0.f, 0.f, 0.f);
      itS[ec + 4 * q + 0][r] = t.x;
      itS[ec + 4 * q + 1][r] = t.y;
      itS[ec + 4 * q + 2][r] = t.z;
      itS[ec + 4 * q + 3][r] = t.w;
    }
    // W row r (d-index) -> WT column pos(r): perfect-shuffle within each 8-block
    int lr = r & 7;
    int rp = (r & ~7) | ((lr < 4) ? (2 * lr) : (2 * (lr - 4) + 1));
    const float4* wp = (const float4*)(W + (size_t)r * 64 + ec);
#pragma unroll
    for (int q = 0; q < 4; ++q) {
      float4 t = wp[q];
      WT[ec + 4 * q + 0][rp] = t.x;
      WT[ec + 4 * q + 1][rp] = t.y;
      WT[ec + 4 * q + 2][rp] = t.z;
      WT[ec + 4 * q + 3][rp] = t.w;
    }
  }
  __syncthreads();

  int ti = tid & 15, td = tid >> 4;
  float acc[4][4];
#pragma unroll
  for (int i = 0; i < 4; ++i)
#pragma unroll
    for (int j = 0; j < 4; ++j) acc[i][j] = 0.f;

#pragma unroll 8
  for (int e = 0; e < 64; ++e) {
    float4 ri = *(const float4*)&itS[e][4 * ti];
    float4 wd = *(const float4*)&WT[e][4 * td];
    float rr[4] = {ri.x, ri.y, ri.z, ri.w};
    float ww[4] = {wd.x, wd.y, wd.z, wd.w};
#pragma unroll
    for (int i = 0; i < 4; ++i)
#pragma unroll
      for (int j = 0; j < 4; ++j) acc[i][j] = fmaf(rr[i], ww[j], acc[i][j]);
  }

#pragma unroll
  for (int i = 0; i < 4; ++i) {
    int gr = r0 + 4 * ti + i;
    if (gr < rMax) {
      float4 o;                   // natural order: WT columns already permuted
      o.x = __builtin_amdgcn_exp2f(acc[i][0] * CSC);
      o.y = __builtin_amdgcn_exp2f(acc[i][1] * CSC);
      o.z = __builtin_amdgcn_exp2f(acc[i][2] * CSC);
      o.w = __builtin_amdgcn_exp2f(acc[i][3] * CSC);
      *(float4*)(dst + (size_t)gr * 64 + 4 * td) = o;
    }
  }
}

// ================= scores: two-group pk interleave (14 pk + 2 rcp per 8 terms) =================
__global__ void __launch_bounds__(256)
scores_kernel(const float* __restrict__ ipE, const float* __restrict__ bpE,
              const float* __restrict__ v, const float* __restrict__ vS,
              float* __restrict__ scores, int N, int B) {
  int tid = threadIdx.x;
  int b0 = blockIdx.y * BT;
  if (b0 > B - BT) b0 = B - BT;              // duplicate-safe clamp
  int n = blockIdx.x * 256 + tid;
  if (n >= N) return;

  float svf;
  {
    double sv = 0.0;
#pragma unroll
    for (int d = 0; d < 64; ++d) sv += (double)v[d]; // uniform, original order
    svf = (float)sv;
  }

  f32x2 acc2[BT];
#pragma unroll
  for (int b = 0; b < BT; ++b) { acc2[b].x = 0.f; acc2[b].y = 0.f; }

  f32x2 one2; one2.x = 1.f; one2.y = 1.f;

#pragma unroll
  for (int half = 0; half < 2; ++half) {
    const f32x2* p   = (const f32x2*)(ipE + (size_t)n * 64 + half * 32);
    const f32x2* vv2 = (const f32x2*)(vS + half * 32);   // uniform -> s_load

#pragma unroll
    for (int b = 0; b < BT; ++b) {
      const f32x2* eb2 = (const f32x2*)(bpE + (size_t)(b0 + b) * 64 + half * 32); // uniform
      f32x2 a = acc2[b];
#pragma unroll
      for (int j = 0; j < 4; ++j) {      // pair-block: groups (2j, 2j+1), 8 terms
        f32x2 E0 = p[4 * j + 0], E1 = p[4 * j + 1], E2 = p[4 * j + 2], E3 = p[4 * j + 3];
        f32x2 B0 = eb2[4 * j + 0], B1 = eb2[4 * j + 1], B2 = eb2[4 * j + 2], B3 = eb2[4 * j + 3];
        f32x2 V0 = vv2[4 * j + 0], V1 = vv2[4 * j + 1], V2 = vv2[4 * j + 2], V3 = vv2[4 * j + 3];
        f32x2 X0 = fma2(B0, E0, one2);   // (x_g0, x_h0)
        f32x2 X1 = fma2(B1, E1, one2);
        f32x2 X2 = fma2(B2, E2, one2);
        f32x2 X3 = fma2(B3, E3, one2);
        f32x2 P01 = X0 * X1, P23 = X2 * X3;
        f32x2 DEN = P01 * P23;                         // (den_g, den_h)
        f32x2 N01 = fma2(V1, X0, V0 * X1);
        f32x2 N23 = fma2(V3, X2, V2 * X3);
        f32x2 NUM = fma2(N23, P01, N01 * P23);         // (num_g, num_h)
        f32x2 R;
        R.x = __builtin_amdgcn_rcpf(DEN.x);            // 2 scalar rcps per 8 terms
        R.y = __builtin_amdgcn_rcpf(DEN.y);
        a = fma2(NUM, R, a);                           // both groups accumulate
      }
      acc2[b] = a;
    }
  }

#pragma unroll
  for (int b = 0; b < BT; ++b)
    scores[(size_t)(b0 + b) * N + n] = fmaf(-2.0f, acc2[b].x + acc2[b].y, svf);
}

// ================= select: sign-split, 2 blocks per row (r13, unchanged) =================
__global__ void __launch_bounds__(1024)
select_kernel(const float* __restrict__ scores, const float* __restrict__ v,
              int* __restrict__ out, int N, int B, int K) {
  __shared__ int lh[NBIN];
  __shared__ int part[64];
  __shared__ u64 cand[CAP];
  __shared__ int cnt, hHi;
  int tid = threadIdx.x;
  int b = blockIdx.x >> 1, side = blockIdx.x & 1;
  const float* row = scores + (size_t)b * N;
  float sgn = side ? -1.f : 1.f;      // side 1: top-k of -s == bottom-k of s

  for (int i = tid; i < NBIN; i += 1024) lh[i] = 0;
  if (tid == 0) cnt = 0;

  // |score| < R = sum|v_d| strictly (|tanh|<1) -> linear bins over [-R, R]
  float R = 0.f;
#pragma unroll
  for (int d = 0; d < 64; ++d) R += fabsf(v[d]);     // uniform
  float invW = (float)NBIN / (2.f * R);
  __syncthreads();

  // pass 1: load (sign-applied) into REGISTERS + histogram
  float4 v4[MAXJ];
#pragma unroll
  for (int j = 0; j < MAXJ; ++j) {
    int f4 = j * 1024 + tid;
    if (j * 4096 < N && f4 * 4 < N) {
      float4 s4 = *(const float4*)(row + (size_t)f4 * 4);
      s4.x *= sgn; s4.y *= sgn; s4.z *= sgn; s4.w *= sgn;
      v4[j] = s4;
      int n0 = f4 * 4;
      float ss[4] = {s4.x, s4.y, s4.z, s4.w};
#pragma unroll
      for (int c = 0; c < 4; ++c) {
        if (n0 + c < N) {
          int bi = (int)((ss[c] + R) * invW);
          bi = bi < 0 ? 0 : (bi > NBIN - 1 ? NBIN - 1 : bi);
          atomicAdd(&lh[bi], 1);
        }
      }
    }
  }
  __syncthreads();

  if (tid < 64) {                  // 64-bin chunk sums
    int s = 0;
    for (int jj = 0; jj < 64; ++jj) s += lh[tid * 64 + jj];
    part[tid] = s;
  }
  __syncthreads();
  if (tid == 0) {                  // threshold bin from the top (of s')
    int cum = 0, c = 63;
    for (; c > 0; --c) { if (cum + part[c] >= K) break; cum += part[c]; }
    int hh = c * 64 + 63;
    for (;; --hh) { cum += lh[hh]; if (cum >= K || hh == 0) break; }
    hHi = hh;
  }
  __syncthreads();
  int hi = hHi;

  // pass 2: compact from registers
#pragma unroll
  for (int j = 0; j < MAXJ; ++j) {
    int f4 = j * 1024 + tid;
    if (j * 4096 < N && f4 * 4 < N) {
      int n0 = f4 * 4;
      float ss[4] = {v4[j].x, v4[j].y, v4[j].z, v4[j].w};
#pragma unroll
      for (int c = 0; c < 4; ++c) {
        if (n0 + c < N) {
          float s = ss[c];
          int bi = (int)((s + R) * invW);
          bi = bi < 0 ? 0 : (bi > NBIN - 1 ? NBIN - 1 : bi);
          if (bi >= hi) { int i = atomicAdd(&cnt, 1); if (i < CAP) cand[i] = packMax(s, n0 + c); }
        }
      }
    }
  }
  __syncthreads();

  // exact rank, O(C^2); keys unique -> ranks unique & complete
  int tP = cnt < CAP ? cnt : CAP;
  int* dst = out + (side ? (size_t)B * K : 0) + (size_t)b * K;
  for (int i = tid; i < tP; i += 1024) {
    u64 key = cand[i]; int r = 0;
    for (int jj = 0; jj < tP; ++jj) r += (cand[jj] > key);
    if (r < K) dst[r] = (int)(~(unsigned)key);
  }
}

extern "C" void kernel_launch(void* const* d_in, const int* in_sizes, int n_in,
                              void* d_out, int out_size, void* d_ws, size_t ws_size,
                              hipStream_t stream) {
  const float* basket = (const float*)d_in[0];
  const float* item   = (const float*)d_in[1];
  const float* Wb     = (const float*)d_in[2];
  const float* Wi     = (const float*)d_in[3];
  const float* v      = (const float*)d_in[4];
  int D = in_sizes[4];           // 64
  int B = in_sizes[0] / D;       // 128
  int N = in_sizes[1] / D;       // 50000
  int K = out_size / (2 * B);    // 50

  float* scores = (float*)d_ws;                         // B*N floats = 25.6 MB
  float* ipE    = scores + (size_t)B * N;               // N*64 floats = 12.8 MB
  float* bpE    = ipE + (size_t)N * 64;                 // B*64 floats = 32 KB
  float* vS     = bpE + (size_t)B * 64;                 // 64 floats (permuted v)

  int nItemBlk = (N + 63) / 64;
  int nBasBlk  = (B + 63) / 64;
  prep_kernel<<<dim3(nItemBlk + nBasBlk), dim3(256), 0, stream>>>(basket, item, Wb, Wi, v, ipE, bpE, vS, N, B, nItemBlk);

  dim3 gs((N + 255) / 256, (B + BT - 1) / BT);
  scores_kernel<<<gs, dim3(256), 0, stream>>>(ipE, bpE, v, vS, scores, N, B);

  select_kernel<<<dim3(2 * B), dim3(1024), 0, stream>>>(scores, v, (int*)d_out, N, B, K);
}

// Round 18
// 72.128 us; speedup vs baseline: 1.0741x; 1.0554x over previous
//
#include <hip/hip_runtime.h>

typedef unsigned long long u64;
typedef float f32x2 __attribute__((ext_vector_type(2)));

#define CSC 2.8853900817779268f   // 2*log2(e): tanh(x) = 1 - 2/(exp2(x*CSC)+1)
#define NBIN 4096
#define CAP  256
#define BT   8
#define MAXJ 16                   // select supports N <= 16*4096

__device__ __forceinline__ f32x2 fma2(f32x2 a, f32x2 b, f32x2 c) {
#if __has_builtin(__builtin_elementwise_fma)
  return __builtin_elementwise_fma(a, b, c);   // -> v_pk_fma_f32
#else
  f32x2 r; r.x = fmaf(a.x, b.x, c.x); r.y = fmaf(a.y, b.y, c.y); return r;
#endif
}

// ---------- sortable key packing ----------
__device__ __forceinline__ unsigned ord32(float f) {
  unsigned u = __float_as_uint(f);
  return (u & 0x80000000u) ? ~u : (u | 0x80000000u);
}
// max-key: descending score, ties -> ascending index (jax.lax.top_k semantics)
__device__ __forceinline__ u64 packMax(float f, int n) {
  return ((u64)ord32(f) << 32) | (unsigned)(~(unsigned)n);
}

// ================= prep: register-tiled projection, GROUP-INTERLEAVED layout (r17) =================
// Each aligned 8-block of output positions holds orig d [0,4,1,5,2,6,3,7]+8j.
// Also writes permuted vS[0:64] and svf = (float)sum_f64(v) at vS[64].
__global__ void __launch_bounds__(256)
prep_kernel(const float* __restrict__ basket, const float* __restrict__ item,
            const float* __restrict__ Wb, const float* __restrict__ Wi,
            const float* __restrict__ v,
            float* __restrict__ ipE, float* __restrict__ bpE, float* __restrict__ vS,
            int N, int B, int nItemBlk) {
  __shared__ float itS[64][64];   // [e][row]
  __shared__ float WT[64][64];    // [e][pos]  (d permuted into pos)
  int tid = threadIdx.x;

  bool isBasket = (blockIdx.x >= nItemBlk);
  const float* src = isBasket ? basket : item;
  const float* W   = isBasket ? Wb : Wi;
  float* dst       = isBasket ? bpE : ipE;
  int r0   = isBasket ? (blockIdx.x - nItemBlk) * 64 : blockIdx.x * 64;
  int rMax = isBasket ? B : N;

  if (blockIdx.x == (unsigned)nItemBlk) {
    if (tid < 64) {                                    // permuted v copy
      int p = tid & 7;
      int d_off = (p & 1) ? (4 + (p >> 1)) : (p >> 1);
      vS[tid] = v[(tid & ~7) | d_off];
    }
    if (tid == 64) {                                   // svf: same f64 order as before
      double sv = 0.0;
#pragma unroll
      for (int d = 0; d < 64; ++d) sv += (double)v[d];
      vS[64] = (float)sv;
    }
  }

  {
    int r = tid & 63, ec = (tid >> 6) * 16;
    const float4* sp = (const float4*)(src + (size_t)(r0 + r) * 64 + ec);
    bool ok = (r0 + r) < rMax;
#pragma unroll
    for (int q = 0; q < 4; ++q) {
      float4 t = ok ? sp[q] : make_float4(0.f, 0.f, 0.f, 0.f);
      itS[ec + 4 * q + 0][r] = t.x;
      itS[ec + 4 * q + 1][r] = t.y;
      itS[ec + 4 * q + 2][r] = t.z;
      itS[ec + 4 * q + 3][r] = t.w;
    }
    // W row r (d-index) -> WT column pos(r): perfect-shuffle within each 8-block
    int lr = r & 7;
    int rp = (r & ~7) | ((lr < 4) ? (2 * lr) : (2 * (lr - 4) + 1));
    const float4* wp = (const float4*)(W + (size_t)r * 64 + ec);
#pragma unroll
    for (int q = 0; q < 4; ++q) {
      float4 t = wp[q];
      WT[ec + 4 * q + 0][rp] = t.x;
      WT[ec + 4 * q + 1][rp] = t.y;
      WT[ec + 4 * q + 2][rp] = t.z;
      WT[ec + 4 * q + 3][rp] = t.w;
    }
  }
  __syncthreads();

  int ti = tid & 15, td = tid >> 4;
  float acc[4][4];
#pragma unroll
  for (int i = 0; i < 4; ++i)
#pragma unroll
    for (int j = 0; j < 4; ++j) acc[i][j] = 0.f;

#pragma unroll 8
  for (int e = 0; e < 64; ++e) {
    float4 ri = *(const float4*)&itS[e][4 * ti];
    float4 wd = *(const float4*)&WT[e][4 * td];
    float rr[4] = {ri.x, ri.y, ri.z, ri.w};
    float ww[4] = {wd.x, wd.y, wd.z, wd.w};
#pragma unroll
    for (int i = 0; i < 4; ++i)
#pragma unroll
      for (int j = 0; j < 4; ++j) acc[i][j] = fmaf(rr[i], ww[j], acc[i][j]);
  }

#pragma unroll
  for (int i = 0; i < 4; ++i) {
    int gr = r0 + 4 * ti + i;
    if (gr < rMax) {
      float4 o;                   // natural order: WT columns already permuted
      o.x = __builtin_amdgcn_exp2f(acc[i][0] * CSC);
      o.y = __builtin_amdgcn_exp2f(acc[i][1] * CSC);
      o.z = __builtin_amdgcn_exp2f(acc[i][2] * CSC);
      o.w = __builtin_amdgcn_exp2f(acc[i][3] * CSC);
      *(float4*)(dst + (size_t)gr * 64 + 4 * td) = o;
    }
  }
}

// ================= scores: two-group pk interleave, svf via s_load =================
__global__ void __launch_bounds__(256)
scores_kernel(const float* __restrict__ ipE, const float* __restrict__ bpE,
              const float* __restrict__ vS, float* __restrict__ scores, int N, int B) {
  int tid = threadIdx.x;
  int b0 = blockIdx.y * BT;
  int n = blockIdx.x * 256 + tid;
  if (n >= N) return;

  float svf = vS[64];             // uniform -> s_load (precomputed in prep)

  f32x2 acc2[BT];
#pragma unroll
  for (int b = 0; b < BT; ++b) { acc2[b].x = 0.f; acc2[b].y = 0.f; }

  f32x2 one2; one2.x = 1.f; one2.y = 1.f;

#pragma unroll
  for (int half = 0; half < 2; ++half) {
    const f32x2* p   = (const f32x2*)(ipE + (size_t)n * 64 + half * 32);
    const f32x2* vv2 = (const f32x2*)(vS + half * 32);   // uniform -> s_load

#pragma unroll
    for (int b = 0; b < BT; ++b) {
      const f32x2* eb2 = (const f32x2*)(bpE + (size_t)(b0 + b) * 64 + half * 32); // uniform
      f32x2 a = acc2[b];
#pragma unroll
      for (int j = 0; j < 4; ++j) {      // pair-block: groups (2j, 2j+1), 8 terms
        f32x2 E0 = p[4 * j + 0], E1 = p[4 * j + 1], E2 = p[4 * j + 2], E3 = p[4 * j + 3];
        f32x2 B0 = eb2[4 * j + 0], B1 = eb2[4 * j + 1], B2 = eb2[4 * j + 2], B3 = eb2[4 * j + 3];
        f32x2 V0 = vv2[4 * j + 0], V1 = vv2[4 * j + 1], V2 = vv2[4 * j + 2], V3 = vv2[4 * j + 3];
        f32x2 X0 = fma2(B0, E0, one2);   // (x_g0, x_h0)
        f32x2 X1 = fma2(B1, E1, one2);
        f32x2 X2 = fma2(B2, E2, one2);
        f32x2 X3 = fma2(B3, E3, one2);
        f32x2 P01 = X0 * X1, P23 = X2 * X3;
        f32x2 DEN = P01 * P23;                         // (den_g, den_h)
        f32x2 N01 = fma2(V1, X0, V0 * X1);
        f32x2 N23 = fma2(V3, X2, V2 * X3);
        f32x2 NUM = fma2(N23, P01, N01 * P23);         // (num_g, num_h)
        f32x2 R;
        R.x = __builtin_amdgcn_rcpf(DEN.x);            // 2 scalar rcps per 8 terms
        R.y = __builtin_amdgcn_rcpf(DEN.y);
        a = fma2(NUM, R, a);                           // both groups accumulate
      }
      acc2[b] = a;
    }
  }

#pragma unroll
  for (int b = 0; b < BT; ++b)
    scores[(size_t)(b0 + b) * N + n] = fmaf(-2.0f, acc2[b].x + acc2[b].y, svf);
}

// ================= select: sign-split, 2 blocks per row (r13, unchanged) =================
__global__ void __launch_bounds__(1024)
select_kernel(const float* __restrict__ scores, const float* __restrict__ v,
              int* __restrict__ out, int N, int B, int K) {
  __shared__ int lh[NBIN];
  __shared__ int part[64];
  __shared__ u64 cand[CAP];
  __shared__ int cnt, hHi;
  int tid = threadIdx.x;
  int b = blockIdx.x >> 1, side = blockIdx.x & 1;
  const float* row = scores + (size_t)b * N;
  float sgn = side ? -1.f : 1.f;      // side 1: top-k of -s == bottom-k of s

  for (int i = tid; i < NBIN; i += 1024) lh[i] = 0;
  if (tid == 0) cnt = 0;

  // |score| < R = sum|v_d| strictly (|tanh|<1) -> linear bins over [-R, R]
  float R = 0.f;
#pragma unroll
  for (int d = 0; d < 64; ++d) R += fabsf(v[d]);     // uniform
  float invW = (float)NBIN / (2.f * R);
  __syncthreads();

  // pass 1: load (sign-applied) into REGISTERS + histogram
  float4 v4[MAXJ];
#pragma unroll
  for (int j = 0; j < MAXJ; ++j) {
    int f4 = j * 1024 + tid;
    if (j * 4096 < N && f4 * 4 < N) {
      float4 s4 = *(const float4*)(row + (size_t)f4 * 4);
      s4.x *= sgn; s4.y *= sgn; s4.z *= sgn; s4.w *= sgn;
      v4[j] = s4;
      int n0 = f4 * 4;
      float ss[4] = {s4.x, s4.y, s4.z, s4.w};
#pragma unroll
      for (int c = 0; c < 4; ++c) {
        if (n0 + c < N) {
          int bi = (int)((ss[c] + R) * invW);
          bi = bi < 0 ? 0 : (bi > NBIN - 1 ? NBIN - 1 : bi);
          atomicAdd(&lh[bi], 1);
        }
      }
    }
  }
  __syncthreads();

  if (tid < 64) {                  // 64-bin chunk sums
    int s = 0;
    for (int jj = 0; jj < 64; ++jj) s += lh[tid * 64 + jj];
    part[tid] = s;
  }
  __syncthreads();
  if (tid == 0) {                  // threshold bin from the top (of s')
    int cum = 0, c = 63;
    for (; c > 0; --c) { if (cum + part[c] >= K) break; cum += part[c]; }
    int hh = c * 64 + 63;
    for (;; --hh) { cum += lh[hh]; if (cum >= K || hh == 0) break; }
    hHi = hh;
  }
  __syncthreads();
  int hi = hHi;

  // pass 2: compact from registers
#pragma unroll
  for (int j = 0; j < MAXJ; ++j) {
    int f4 = j * 1024 + tid;
    if (j * 4096 < N && f4 * 4 < N) {
      int n0 = f4 * 4;
      float ss[4] = {v4[j].x, v4[j].y, v4[j].z, v4[j].w};
#pragma unroll
      for (int c = 0; c < 4; ++c) {
        if (n0 + c < N) {
          float s = ss[c];
          int bi = (int)((s + R) * invW);
          bi = bi < 0 ? 0 : (bi > NBIN - 1 ? NBIN - 1 : bi);
          if (bi >= hi) { int i = atomicAdd(&cnt, 1); if (i < CAP) cand[i] = packMax(s, n0 + c); }
        }
      }
    }
  }
  __syncthreads();

  // exact rank, O(C^2); keys unique -> ranks unique & complete
  int tP = cnt < CAP ? cnt : CAP;
  int* dst = out + (side ? (size_t)B * K : 0) + (size_t)b * K;
  for (int i = tid; i < tP; i += 1024) {
    u64 key = cand[i]; int r = 0;
    for (int jj = 0; jj < tP; ++jj) r += (cand[jj] > key);
    if (r < K) dst[r] = (int)(~(unsigned)key);
  }
}

extern "C" void kernel_launch(void* const* d_in, const int* in_sizes, int n_in,
                              void* d_out, int out_size, void* d_ws, size_t ws_size,
                              hipStream_t stream) {
  const float* basket = (const float*)d_in[0];
  const float* item   = (const float*)d_in[1];
  const float* Wb     = (const float*)d_in[2];
  const float* Wi     = (const float*)d_in[3];
  const float* v      = (const float*)d_in[4];
  int D = in_sizes[4];           // 64
  int B = in_sizes[0] / D;       // 128
  int N = in_sizes[1] / D;       // 50000
  int K = out_size / (2 * B);    // 50

  float* scores = (float*)d_ws;                         // B*N floats = 25.6 MB
  float* ipE    = scores + (size_t)B * N;               // N*64 floats = 12.8 MB
  float* bpE    = ipE + (size_t)N * 64;                 // B*64 floats = 32 KB
  float* vS     = bpE + (size_t)B * 64;                 // 65 floats (permuted v + svf)

  int nItemBlk = (N + 63) / 64;
  int nBasBlk  = (B + 63) / 64;
  prep_kernel<<<dim3(nItemBlk + nBasBlk), dim3(256), 0, stream>>>(basket, item, Wb, Wi, v, ipE, bpE, vS, N, B, nItemBlk);

  dim3 gs((N + 255) / 256, (B + BT - 1) / BT);
  scores_kernel<<<gs, dim3(256), 0, stream>>>(ipE, bpE, vS, scores, N, B);

  select_kernel<<<dim3(2 * B), dim3(1024), 0, stream>>>(scores, v, (int*)d_out, N, B, K);
}